// Round 5
// baseline (208.996 us; speedup 1.0000x reference)
//
#include <hip/hip_runtime.h>
#include <hip/hip_bf16.h>
#include <cstddef>

// 3-layer tanh RNN (B=8192, T=80, D=32, H=64), fused, MFMA.
// SYSTOLIC LAYER PIPELINE (1 barrier/tick) x J-SPLIT-2 (occupancy).
//
// Block = 384 thr = 6 waves = (layer l in 0..2) x (j-half s in 0..1); 16 batch rows.
// Wave (l,s) computes layer l, units j in [32s, 32s+32), at local time lt = tau - l.
// 512 blocks -> 12 waves/CU = 3 waves/SIMD; ONE __syncthreads per tick (82 ticks).
//
// MFMA 16x16x32 bf16, A = weights (VGPR-resident), B = activations:
//   A-frag: lane holds A[m=lane&15][k=8*(lane>>4)+i]
//   B-frag: lane holds B[k=8*(lane>>4)+i][n=lane&15]
//   C/D:    lane holds D[row=4*(lane>>4)+r][col=lane&15]     (verified R2-R4)
// h exchange: hb[layer][t&1][batch][j] (stride 72 shorts, +8 pad). Writer: 2x
// ds_write_b64 (one per j-tile); reader: ds_read_b128 per 32-k half.
// Latency hiding: own j-half of the recurrence is read back PRE-barrier (same-wave
// DS order => RAW safe) so wh_own*r_own issues with register-ready operands at the
// next tick; sibling half + upstream come from post-barrier LDS reads, hidden by
// the 3-waves/SIMD co-residency. t=0 state = register zeros (no LDS init).

typedef __attribute__((ext_vector_type(8))) short s16x8;
typedef __attribute__((ext_vector_type(4))) short s16x4;
typedef __attribute__((ext_vector_type(4))) float fx4;

#define MFMA16(A, B, C) __builtin_amdgcn_mfma_f32_16x16x32_bf16((A), (B), (C), 0, 0, 0)

#if __has_builtin(__builtin_amdgcn_exp2f)
#define EXP2F(x) __builtin_amdgcn_exp2f(x)
#else
#define EXP2F(x) exp2f(x)
#endif
#if __has_builtin(__builtin_amdgcn_rcpf)
#define RCPF(x) __builtin_amdgcn_rcpf(x)
#else
#define RCPF(x) (1.0f / (x))
#endif

static constexpr float K2LOG2E = 2.8853900817779268f;  // 2*log2(e)

__device__ __forceinline__ short f2bf(float f) {  // RNE float->bf16 (weights, one-time)
  union { float f; unsigned u; } v; v.f = f;
  unsigned r = v.u + 0x7FFFu + ((v.u >> 16) & 1u);
  return (short)(r >> 16);
}
__device__ __forceinline__ float bf2f(short s) {
  union { unsigned u; float f; } v; v.u = ((unsigned)(unsigned short)s) << 16;
  return v.f;
}
__device__ __forceinline__ unsigned pk2bf(float a, float b) {  // v_cvt_pk_bf16_f32
  float2 t; t.x = a; t.y = b;
  union { __hip_bfloat162 h; unsigned u; } c;
  c.h = __float22bfloat162_rn(t);
  return c.u;
}

__device__ __forceinline__ s16x8 wfragA(const float* W, int ncols, int row, int col0) {
  const float* p = W + row * ncols + col0;
  s16x8 r;
#pragma unroll
  for (int i = 0; i < 8; ++i) r[i] = f2bf(p[i]);
  return r;
}

__global__ __launch_bounds__(384, 3) void rnn3_pipe6(
    const float* __restrict__ x,
    const float* __restrict__ Wih0, const float* __restrict__ Whh0,
    const float* __restrict__ bih0, const float* __restrict__ bhh0,
    const float* __restrict__ Wih1, const float* __restrict__ Whh1,
    const float* __restrict__ bih1, const float* __restrict__ bhh1,
    const float* __restrict__ Wih2, const float* __restrict__ Whh2,
    const float* __restrict__ bih2, const float* __restrict__ bhh2,
    const float* __restrict__ Wfc, const float* __restrict__ bfc,
    float* __restrict__ out)
{
  __shared__ __align__(16) short hb[3][2][16][72];  // [layer][t&1][batch][j], 13824 B

  const int tid = threadIdx.x;
  const int wvu = __builtin_amdgcn_readfirstlane(tid >> 6);  // 0..5, wave-uniform
  const int l   = wvu >> 1;       // layer this wave owns
  const int s   = wvu & 1;        // j-half this wave owns
  const int ln  = tid & 63;
  const int q   = ln >> 4;
  const int m15 = ln & 15;
  const int bbase = (int)blockIdx.x * 16;

  // ---------- this wave's layer parameters (SGPR-held) ----------
  const float* Wih = (l == 0) ? Wih0 : (l == 1) ? Wih1 : Wih2;
  const float* Whh = (l == 0) ? Whh0 : (l == 1) ? Whh1 : Whh2;
  const float* bi  = (l == 0) ? bih0 : (l == 1) ? bih1 : bih2;
  const float* bh  = (l == 0) ? bhh0 : (l == 1) ? bhh1 : bhh2;
  const int kin = (l == 0) ? 32 : 64;

  // ---------- weight A-fragments: 2 j-tiles, rows j = 32s + 16*tile + m15 --------
  // whOwn covers k in [32s,32s+32) (pairs with the pre-barrier own-half readback);
  // whOth covers the sibling's k-half.
  const s16x8 z8 = {0, 0, 0, 0, 0, 0, 0, 0};
  s16x8 wi0[2], wi1[2], whOwn[2], whOth[2];
#pragma unroll
  for (int tile = 0; tile < 2; ++tile) {
    const int row = 32 * s + 16 * tile + m15;
    wi0[tile]   = wfragA(Wih, kin, row, 8 * q);
    wi1[tile]   = l ? wfragA(Wih, 64, row, 32 + 8 * q) : z8;  // layer 0: K=32 only
    whOwn[tile] = wfragA(Whh, 64, row, 32 * s + 8 * q);
    whOth[tile] = wfragA(Whh, 64, row, 32 * (1 - s) + 8 * q);
  }

  // ---------- biases pre-scaled by 2*log2(e); lane's j = 32s + 16*tile + 4q + r --
  float bsc[2][4];
#pragma unroll
  for (int tile = 0; tile < 2; ++tile)
#pragma unroll
    for (int r = 0; r < 4; ++r) {
      const int j = 32 * s + 16 * tile + 4 * q + r;
      bsc[tile][r] = (bi[j] + bh[j]) * K2LOG2E;
    }

  // ---------- LDS pointers, both parities precomputed ----------
  short*       wr_[2]  = {&hb[l][0][m15][32 * s + 4 * q], &hb[l][1][m15][32 * s + 4 * q]};
  const short* own_[2] = {&hb[l][0][m15][32 * s + 8 * q], &hb[l][1][m15][32 * s + 8 * q]};
  const short* oth_[2] = {&hb[l][0][m15][32 * (1 - s) + 8 * q],
                          &hb[l][1][m15][32 * (1 - s) + 8 * q]};
  const int lup = (l == 0) ? 0 : l - 1;   // dummy 0 for layer 0 (never read)
  const short* up_[2]  = {&hb[lup][0][m15][8 * q], &hb[lup][1][m15][8 * q]};

  // x source (layer-0 waves): lane reads x[bbase+m15][t][8q..8q+7], prefetched
  const float* xr = x + (size_t)(bbase + m15) * (80 * 32) + 8 * q;
  fx4 xc0 = {0, 0, 0, 0}, xc1 = {0, 0, 0, 0};
  if (l == 0) { xc0 = *(const fx4*)(xr); xc1 = *(const fx4*)(xr + 4); }

  const fx4 z4 = {0.f, 0.f, 0.f, 0.f};
  s16x8 rOwn = z8;                 // own j-half of h_l(lt-1), pre-barrier readback

  for (int tau = 0; tau < 82; ++tau) {
    const int lt = tau - l;                 // this wave's time step (wave-uniform)
    if (0 <= lt && lt < 80) {
      const int p  = lt & 1;
      const int pm = p ^ 1;                 // parity of lt-1
      // ---- sibling half of own recurrence (written by sibling wave last tick) ----
      s16x8 rOth = z8;
      if (lt > 0) rOth = *(const s16x8*)(oth_[pm]);
      // ---- upstream input B-frags ----
      s16x8 in0, in1 = z8;
      if (l == 0) {
        union { unsigned u[4]; s16x8 v; } xp;
        xp.u[0] = pk2bf(xc0[0], xc0[1]); xp.u[1] = pk2bf(xc0[2], xc0[3]);
        xp.u[2] = pk2bf(xc1[0], xc1[1]); xp.u[3] = pk2bf(xc1[2], xc1[3]);
        in0 = xp.v;
        const int tn = (lt < 79) ? lt + 1 : 79;          // prefetch x(t+1)
        xc0 = *(const fx4*)(xr + tn * 32);
        xc1 = *(const fx4*)(xr + tn * 32 + 4);
      } else {
        const short* up = up_[p];
        in0 = *(const s16x8*)(up);
        in1 = *(const s16x8*)(up + 32);
      }
      // ---- MFMA: whOwn*rOwn first (register-ready) to hide the LDS reads ----
      fx4 acc[2];
#pragma unroll
      for (int tile = 0; tile < 2; ++tile) acc[tile] = MFMA16(whOwn[tile], rOwn, z4);
#pragma unroll
      for (int tile = 0; tile < 2; ++tile) acc[tile] = MFMA16(whOth[tile], rOth, acc[tile]);
#pragma unroll
      for (int tile = 0; tile < 2; ++tile) acc[tile] = MFMA16(wi0[tile], in0, acc[tile]);
      if (l) {
#pragma unroll
        for (int tile = 0; tile < 2; ++tile) acc[tile] = MFMA16(wi1[tile], in1, acc[tile]);
      }
      // ---- tanh + pack + store h_l(lt) (2x ds_write_b64) ----
      short* wb = wr_[p];
#pragma unroll
      for (int tile = 0; tile < 2; ++tile) {
        float h[4];
#pragma unroll
        for (int r = 0; r < 4; ++r) {
          float e = EXP2F(__builtin_fmaf(acc[tile][r], K2LOG2E, bsc[tile][r]));
          h[r] = __builtin_fmaf(-2.f, RCPF(e + 1.f), 1.f);
        }
        union { unsigned u[2]; s16x4 v; } pk;
        pk.u[0] = pk2bf(h[0], h[1]);
        pk.u[1] = pk2bf(h[2], h[3]);
        *(s16x4*)(wb + 16 * tile) = pk.v;
      }
      // ---- own-half transpose readback (pre-barrier; same-wave RAW safe) ----
      rOwn = *(const s16x8*)(own_[p]);
    }
    __syncthreads();                        // ONE barrier per tick
  }

  // ---------- FC head: h2(79) is in hb[2][1] (parity of t=79) ----------
  if (wvu == 4) {
    const short* f = &hb[2][1][m15][8 * q];
    s16x8 f0 = *(const s16x8*)(f);
    s16x8 f1 = *(const s16x8*)(f + 32);
    float sv = 0.f;
#pragma unroll
    for (int i = 0; i < 8; ++i) sv += bf2f(f0[i]) * Wfc[8 * q + i];
#pragma unroll
    for (int i = 0; i < 8; ++i) sv += bf2f(f1[i]) * Wfc[32 + 8 * q + i];
    sv += __shfl_xor(sv, 16, 64);
    sv += __shfl_xor(sv, 32, 64);
    if (ln < 16) out[bbase + ln] = sv + bfc[0];
  }
}

extern "C" void kernel_launch(void* const* d_in, const int* in_sizes, int n_in,
                              void* d_out, int out_size, void* d_ws, size_t ws_size,
                              hipStream_t stream) {
  const float* x    = (const float*)d_in[0];
  const float* Wih0 = (const float*)d_in[1];
  const float* Whh0 = (const float*)d_in[2];
  const float* bih0 = (const float*)d_in[3];
  const float* bhh0 = (const float*)d_in[4];
  const float* Wih1 = (const float*)d_in[5];
  const float* Whh1 = (const float*)d_in[6];
  const float* bih1 = (const float*)d_in[7];
  const float* bhh1 = (const float*)d_in[8];
  const float* Wih2 = (const float*)d_in[9];
  const float* Whh2 = (const float*)d_in[10];
  const float* bih2 = (const float*)d_in[11];
  const float* bhh2 = (const float*)d_in[12];
  const float* Wfc  = (const float*)d_in[13];
  const float* bfc  = (const float*)d_in[14];

  // 512 blocks x 384 thr (6 waves = 3 layers x 2 j-halves), 16 batch rows per block.
  // 12 waves/CU = 3 waves/SIMD.
  rnn3_pipe6<<<dim3(512), dim3(384), 0, stream>>>(
      x, Wih0, Whh0, bih0, bhh0, Wih1, Whh1, bih1, bhh1,
      Wih2, Whh2, bih2, bhh2, Wfc, bfc, (float*)d_out);
}